// Round 1
// baseline (375.038 us; speedup 1.0000x reference)
//
#include <hip/hip_runtime.h>

// Problem: B=32, LQ=1024, LKV=1024, D=512, fp32.
// out = [output (B*LQ*D), attn (B*LQ*LKV)] concatenated, fp32.

constexpr int NB  = 32;
constexpr int LQ  = 1024;
constexpr int LKV = 1024;
constexpr int DD  = 512;

typedef __attribute__((ext_vector_type(4))) float f4;
typedef __attribute__((ext_vector_type(4))) float f32x4;
typedef __attribute__((ext_vector_type(4))) unsigned short u16x4;
typedef __attribute__((ext_vector_type(8))) __bf16 bf16x8;

__device__ __forceinline__ unsigned short f2bf(float x) {
  unsigned u = __builtin_bit_cast(unsigned, x);
  unsigned r = u + 0x7FFFu + ((u >> 16) & 1u);   // round-to-nearest-even
  return (unsigned short)(r >> 16);
}
__device__ __forceinline__ float bf2f(unsigned short h) {
  unsigned u = ((unsigned)h) << 16;
  return __builtin_bit_cast(float, u);
}

constexpr int PAD = 40;   // 32 k-elems + 8 pad (16B-aligned rows, ~2-way banks)

// ---------------------------------------------------------------------------
// Kernel 1: S[b] = Q[b] @ KV[b]^T  (split-bf16, 3 MFMA per product, fp32-grade)
// Writes raw scores into the attn region of d_out.
// ---------------------------------------------------------------------------
__global__ __launch_bounds__(256) void gemm_qk_kernel(const float* __restrict__ Q,
                                                      const float* __restrict__ KV,
                                                      float* __restrict__ S)
{
  __shared__ unsigned short Ah[128][PAD], Al[128][PAD], Bh[128][PAD], Bl[128][PAD];
  const int b   = blockIdx.y;
  const int ti  = blockIdx.x >> 3;   // LQ tile  (0..7)
  const int tj  = blockIdx.x & 7;    // LKV tile (0..7)
  const int tid  = threadIdx.x;
  const int lane = tid & 63;
  const int wid  = tid >> 6;
  const int wr = (wid >> 1) * 64;    // wave row offset in 128x128 tile
  const int wc = (wid & 1) * 64;

  const float* Qb = Q  + (size_t)b * LQ  * DD + (size_t)ti * 128 * DD;
  const float* Kb = KV + (size_t)b * LKV * DD + (size_t)tj * 128 * DD;

  f32x4 acc[4][4] = {};

  for (int ks = 0; ks < DD; ks += 32) {
    __syncthreads();
    // stage 128x32 of Q and of KV, converting fp32 -> bf16 hi/lo
#pragma unroll
    for (int i = 0; i < 4; ++i) {
      int idx = tid + i * 256;         // 0..1023
      int r   = idx >> 3;              // 0..127
      int k4  = (idx & 7) << 2;        // 0,4,...,28
      f4 qa = *(const f4*)(Qb + (size_t)r * DD + ks + k4);
      f4 ka = *(const f4*)(Kb + (size_t)r * DD + ks + k4);
      u16x4 qh, ql, kh, kl;
#pragma unroll
      for (int u = 0; u < 4; ++u) {
        unsigned short h = f2bf(qa[u]);
        qh[u] = h;  ql[u] = f2bf(qa[u] - bf2f(h));
        unsigned short h2 = f2bf(ka[u]);
        kh[u] = h2; kl[u] = f2bf(ka[u] - bf2f(h2));
      }
      *(u16x4*)&Ah[r][k4] = qh;  *(u16x4*)&Al[r][k4] = ql;
      *(u16x4*)&Bh[r][k4] = kh;  *(u16x4*)&Bl[r][k4] = kl;
    }
    __syncthreads();

    const int kf = (lane >> 4) << 3;   // 0,8,16,24
    bf16x8 ah[4], al[4], bh[4], bl[4];
#pragma unroll
    for (int m = 0; m < 4; ++m) {
      int row = wr + m * 16 + (lane & 15);
      ah[m] = *(const bf16x8*)&Ah[row][kf];
      al[m] = *(const bf16x8*)&Al[row][kf];
    }
#pragma unroll
    for (int n = 0; n < 4; ++n) {
      int row = wc + n * 16 + (lane & 15);
      bh[n] = *(const bf16x8*)&Bh[row][kf];
      bl[n] = *(const bf16x8*)&Bl[row][kf];
    }
#pragma unroll
    for (int m = 0; m < 4; ++m)
#pragma unroll
      for (int n = 0; n < 4; ++n) {
        acc[m][n] = __builtin_amdgcn_mfma_f32_16x16x32_bf16(ah[m], bh[n], acc[m][n], 0, 0, 0);
        acc[m][n] = __builtin_amdgcn_mfma_f32_16x16x32_bf16(ah[m], bl[n], acc[m][n], 0, 0, 0);
        acc[m][n] = __builtin_amdgcn_mfma_f32_16x16x32_bf16(al[m], bh[n], acc[m][n], 0, 0, 0);
      }
  }

  float* Sb = S + (size_t)b * LQ * LKV;
#pragma unroll
  for (int m = 0; m < 4; ++m) {
    int row0 = ti * 128 + wr + m * 16 + ((lane >> 4) << 2);
#pragma unroll
    for (int n = 0; n < 4; ++n) {
      int col = tj * 128 + wc + n * 16 + (lane & 15);
#pragma unroll
      for (int j = 0; j < 4; ++j)
        Sb[(size_t)(row0 + j) * LKV + col] = acc[m][n][j];
    }
  }
}

// ---------------------------------------------------------------------------
// Kernel 2: in-place row softmax over the attn region (rows of 1024 fp32)
// ---------------------------------------------------------------------------
__global__ __launch_bounds__(256) void softmax_kernel(float* __restrict__ S)
{
  __shared__ float redmax[4], redsum[4];
  const int tid = threadIdx.x;
  float* p = S + (size_t)blockIdx.x * LKV;

  f4 v = *(const f4*)(p + tid * 4);
  float mx = fmaxf(fmaxf(v[0], v[1]), fmaxf(v[2], v[3]));
#pragma unroll
  for (int off = 32; off >= 1; off >>= 1)
    mx = fmaxf(mx, __shfl_xor(mx, off));
  if ((tid & 63) == 0) redmax[tid >> 6] = mx;
  __syncthreads();
  mx = fmaxf(fmaxf(redmax[0], redmax[1]), fmaxf(redmax[2], redmax[3]));

  f4 e;
#pragma unroll
  for (int u = 0; u < 4; ++u) e[u] = __expf(v[u] - mx);
  float sm = e[0] + e[1] + e[2] + e[3];
#pragma unroll
  for (int off = 32; off >= 1; off >>= 1)
    sm += __shfl_xor(sm, off);
  if ((tid & 63) == 0) redsum[tid >> 6] = sm;
  __syncthreads();
  sm = redsum[0] + redsum[1] + redsum[2] + redsum[3];

  float inv = 1.0f / sm;
  f4 o = { e[0] * inv, e[1] * inv, e[2] * inv, e[3] * inv };
  *(f4*)(p + tid * 4) = o;
}

// ---------------------------------------------------------------------------
// Kernel 3: O[b] = A[b] @ KV[b]   (plain bf16 MFMA; A in [0,1], tolerant)
// ---------------------------------------------------------------------------
__global__ __launch_bounds__(256) void gemm_av_kernel(const float* __restrict__ A,
                                                      const float* __restrict__ KV,
                                                      float* __restrict__ O)
{
  __shared__ unsigned short Ab[128][PAD], Bt[128][PAD];
  const int b  = blockIdx.z;
  const int mi = blockIdx.y;     // 0..7  (LQ tiles)
  const int nj = blockIdx.x;     // 0..3  (D tiles)
  const int tid  = threadIdx.x;
  const int lane = tid & 63;
  const int wid  = tid >> 6;
  const int wr = (wid >> 1) * 64;
  const int wc = (wid & 1) * 64;

  const float* Arow = A  + (size_t)b * LQ * LKV + (size_t)mi * 128 * LKV;
  const float* Kb   = KV + (size_t)b * LKV * DD;

  f32x4 acc[4][4] = {};

  for (int ks = 0; ks < LKV; ks += 32) {
    __syncthreads();
#pragma unroll
    for (int i = 0; i < 4; ++i) {
      int idx = tid + i * 256;          // 0..1023
      // A tile: 128 rows x 32 k (k-contiguous)
      {
        int r  = idx >> 3;
        int k4 = (idx & 7) << 2;
        f4 av = *(const f4*)(Arow + (size_t)r * LKV + ks + k4);
        u16x4 h;
#pragma unroll
        for (int u = 0; u < 4; ++u) h[u] = f2bf(av[u]);
        *(u16x4*)&Ab[r][k4] = h;
      }
      // B tile: KV[ks+kr][nj*128 + c] -> transposed Bt[c][kr]
      {
        int kr = idx >> 5;                // 0..31
        int c4 = (idx & 31) << 2;         // 0,4,...,124
        f4 kv = *(const f4*)(Kb + (size_t)(ks + kr) * DD + nj * 128 + c4);
        unsigned short hv[4];
#pragma unroll
        for (int u = 0; u < 4; ++u) hv[u] = f2bf(kv[u]);
#pragma unroll
        for (int u = 0; u < 4; ++u) {
          int uu = (u + kr) & 3;          // rotate to spread LDS banks
          Bt[c4 + uu][kr] = hv[uu];
        }
      }
    }
    __syncthreads();

    const int kf = (lane >> 4) << 3;
    bf16x8 af[4], bfv[4];
#pragma unroll
    for (int m = 0; m < 4; ++m)
      af[m] = *(const bf16x8*)&Ab[wr + m * 16 + (lane & 15)][kf];
#pragma unroll
    for (int n = 0; n < 4; ++n)
      bfv[n] = *(const bf16x8*)&Bt[wc + n * 16 + (lane & 15)][kf];
#pragma unroll
    for (int m = 0; m < 4; ++m)
#pragma unroll
      for (int n = 0; n < 4; ++n)
        acc[m][n] = __builtin_amdgcn_mfma_f32_16x16x32_bf16(af[m], bfv[n], acc[m][n], 0, 0, 0);
  }

  float* Ob = O + (size_t)b * LQ * DD;
#pragma unroll
  for (int m = 0; m < 4; ++m) {
    int row0 = mi * 128 + wr + m * 16 + ((lane >> 4) << 2);
#pragma unroll
    for (int n = 0; n < 4; ++n) {
      int col = nj * 128 + wc + n * 16 + (lane & 15);
#pragma unroll
      for (int j = 0; j < 4; ++j)
        Ob[(size_t)(row0 + j) * DD + col] = acc[m][n][j];
    }
  }
}

// ---------------------------------------------------------------------------
extern "C" void kernel_launch(void* const* d_in, const int* in_sizes, int n_in,
                              void* d_out, int out_size, void* d_ws, size_t ws_size,
                              hipStream_t stream) {
  const float* Q  = (const float*)d_in[0];
  const float* KV = (const float*)d_in[1];
  float* out  = (float*)d_out;                       // B*LQ*D
  float* attn = out + (size_t)NB * LQ * DD;          // B*LQ*LKV

  // 1) raw scores -> attn region
  gemm_qk_kernel<<<dim3((LQ / 128) * (LKV / 128), NB), 256, 0, stream>>>(Q, KV, attn);
  // 2) softmax in place
  softmax_kernel<<<dim3(NB * LQ), 256, 0, stream>>>(attn);
  // 3) output = attn @ KV
  gemm_av_kernel<<<dim3(DD / 128, LQ / 128, NB), 256, 0, stream>>>(attn, KV, out);
}

// Round 2
// 290.661 us; speedup vs baseline: 1.2903x; 1.2903x over previous
//
#include <hip/hip_runtime.h>

// Problem: B=32, LQ=1024, LKV=1024, D=512, fp32.
// out = [output (B*LQ*D), attn (B*LQ*LKV)] concatenated, fp32.

constexpr int NB  = 32;
constexpr int LQ  = 1024;
constexpr int LKV = 1024;
constexpr int DD  = 512;

typedef __attribute__((ext_vector_type(4))) float f4;
typedef __attribute__((ext_vector_type(4))) float f32x4;
typedef __attribute__((ext_vector_type(4))) unsigned short u16x4;
typedef __attribute__((ext_vector_type(8))) __bf16 bf16x8;

__device__ __forceinline__ unsigned short f2bf(float x) {
  unsigned u = __builtin_bit_cast(unsigned, x);
  unsigned r = u + 0x7FFFu + ((u >> 16) & 1u);   // round-to-nearest-even
  return (unsigned short)(r >> 16);
}
__device__ __forceinline__ float bf2f(unsigned short h) {
  unsigned u = ((unsigned)h) << 16;
  return __builtin_bit_cast(float, u);
}

__device__ __forceinline__ void gload16(const void* g, void* l) {
  __builtin_amdgcn_global_load_lds((const __attribute__((address_space(1))) unsigned int*)g,
                                   (__attribute__((address_space(3))) unsigned int*)l,
                                   16, 0, 0);
}

constexpr int PAD = 40;   // for qk kernel + fallback av

// ---------------------------------------------------------------------------
// Kernel 1: S[b] = Q[b] @ KV[b]^T  (split-bf16, 3 MFMA per product, fp32-grade)
// ---------------------------------------------------------------------------
__global__ __launch_bounds__(256) void gemm_qk_kernel(const float* __restrict__ Q,
                                                      const float* __restrict__ KV,
                                                      float* __restrict__ S)
{
  __shared__ unsigned short Ah[128][PAD], Al[128][PAD], Bh[128][PAD], Bl[128][PAD];
  const int b   = blockIdx.y;
  const int ti  = blockIdx.x >> 3;   // LQ tile  (0..7)
  const int tj  = blockIdx.x & 7;    // LKV tile (0..7)
  const int tid  = threadIdx.x;
  const int lane = tid & 63;
  const int wid  = tid >> 6;
  const int wr = (wid >> 1) * 64;
  const int wc = (wid & 1) * 64;

  const float* Qb = Q  + (size_t)b * LQ  * DD + (size_t)ti * 128 * DD;
  const float* Kb = KV + (size_t)b * LKV * DD + (size_t)tj * 128 * DD;

  f32x4 acc[4][4] = {};

  for (int ks = 0; ks < DD; ks += 32) {
    __syncthreads();
#pragma unroll
    for (int i = 0; i < 4; ++i) {
      int idx = tid + i * 256;
      int r   = idx >> 3;
      int k4  = (idx & 7) << 2;
      f4 qa = *(const f4*)(Qb + (size_t)r * DD + ks + k4);
      f4 ka = *(const f4*)(Kb + (size_t)r * DD + ks + k4);
      u16x4 qh, ql, kh, kl;
#pragma unroll
      for (int u = 0; u < 4; ++u) {
        unsigned short h = f2bf(qa[u]);
        qh[u] = h;  ql[u] = f2bf(qa[u] - bf2f(h));
        unsigned short h2 = f2bf(ka[u]);
        kh[u] = h2; kl[u] = f2bf(ka[u] - bf2f(h2));
      }
      *(u16x4*)&Ah[r][k4] = qh;  *(u16x4*)&Al[r][k4] = ql;
      *(u16x4*)&Bh[r][k4] = kh;  *(u16x4*)&Bl[r][k4] = kl;
    }
    __syncthreads();

    const int kf = (lane >> 4) << 3;
    bf16x8 ah[4], al[4], bh[4], bl[4];
#pragma unroll
    for (int m = 0; m < 4; ++m) {
      int row = wr + m * 16 + (lane & 15);
      ah[m] = *(const bf16x8*)&Ah[row][kf];
      al[m] = *(const bf16x8*)&Al[row][kf];
    }
#pragma unroll
    for (int n = 0; n < 4; ++n) {
      int row = wc + n * 16 + (lane & 15);
      bh[n] = *(const bf16x8*)&Bh[row][kf];
      bl[n] = *(const bf16x8*)&Bl[row][kf];
    }
#pragma unroll
    for (int m = 0; m < 4; ++m)
#pragma unroll
      for (int n = 0; n < 4; ++n) {
        acc[m][n] = __builtin_amdgcn_mfma_f32_16x16x32_bf16(ah[m], bh[n], acc[m][n], 0, 0, 0);
        acc[m][n] = __builtin_amdgcn_mfma_f32_16x16x32_bf16(ah[m], bl[n], acc[m][n], 0, 0, 0);
        acc[m][n] = __builtin_amdgcn_mfma_f32_16x16x32_bf16(al[m], bh[n], acc[m][n], 0, 0, 0);
      }
  }

  float* Sb = S + (size_t)b * LQ * LKV;
#pragma unroll
  for (int m = 0; m < 4; ++m) {
    int row0 = ti * 128 + wr + m * 16 + ((lane >> 4) << 2);
#pragma unroll
    for (int n = 0; n < 4; ++n) {
      int col = tj * 128 + wc + n * 16 + (lane & 15);
#pragma unroll
      for (int j = 0; j < 4; ++j)
        Sb[(size_t)(row0 + j) * LKV + col] = acc[m][n][j];
    }
  }
}

// ---------------------------------------------------------------------------
// Kernel 2: in-place row softmax (rows of 1024 fp32)
// ---------------------------------------------------------------------------
__global__ __launch_bounds__(256) void softmax_kernel(float* __restrict__ S)
{
  __shared__ float redmax[4], redsum[4];
  const int tid = threadIdx.x;
  float* p = S + (size_t)blockIdx.x * LKV;

  f4 v = *(const f4*)(p + tid * 4);
  float mx = fmaxf(fmaxf(v[0], v[1]), fmaxf(v[2], v[3]));
#pragma unroll
  for (int off = 32; off >= 1; off >>= 1)
    mx = fmaxf(mx, __shfl_xor(mx, off));
  if ((tid & 63) == 0) redmax[tid >> 6] = mx;
  __syncthreads();
  mx = fmaxf(fmaxf(redmax[0], redmax[1]), fmaxf(redmax[2], redmax[3]));

  f4 e;
#pragma unroll
  for (int u = 0; u < 4; ++u) e[u] = __expf(v[u] - mx);
  float sm = e[0] + e[1] + e[2] + e[3];
#pragma unroll
  for (int off = 32; off >= 1; off >>= 1)
    sm += __shfl_xor(sm, off);
  if ((tid & 63) == 0) redsum[tid >> 6] = sm;
  __syncthreads();
  sm = redsum[0] + redsum[1] + redsum[2] + redsum[3];

  float inv = 1.0f / sm;
  f4 o = { e[0] * inv, e[1] * inv, e[2] * inv, e[3] * inv };
  *(f4*)(p + tid * 4) = o;
}

// ---------------------------------------------------------------------------
// Prep: KVT[b][d][kv] (bf16) = transpose of KV[b][kv][d] (fp32).
// 64x64 tile per block via padded LDS; coalesced read and write.
// ---------------------------------------------------------------------------
__global__ __launch_bounds__(256) void kvt_prep_kernel(const float* __restrict__ KV,
                                                       unsigned short* __restrict__ KVT)
{
  __shared__ unsigned short T[64][72];
  const int b  = blockIdx.z;
  const int tk = blockIdx.y;   // kv tile (64 wide), 0..15
  const int td = blockIdx.x;   // d  tile (64 wide), 0..7
  const int tid = threadIdx.x;

  // load: rows = kv, cols = d (coalesced 16B per lane)
#pragma unroll
  for (int i = 0; i < 4; ++i) {
    int idx = tid + i * 256;            // 0..1023
    int r   = idx >> 4;                 // kv row 0..63
    int c4  = (idx & 15) << 2;          // d col 0,4,..,60
    f4 v = *(const f4*)(KV + ((size_t)b * LKV + tk * 64 + r) * DD + td * 64 + c4);
    u16x4 h;
#pragma unroll
    for (int u = 0; u < 4; ++u) h[u] = f2bf(v[u]);
    *(u16x4*)&T[r][c4] = h;
  }
  __syncthreads();

  // store transposed: rows = d, cols = kv (coalesced 8B per lane)
#pragma unroll
  for (int i = 0; i < 4; ++i) {
    int idx = tid + i * 256;
    int c   = idx >> 4;                 // d row 0..63
    int r4  = (idx & 15) << 2;          // kv col 0,4,..,60
    u16x4 w = { T[r4][c], T[r4 + 1][c], T[r4 + 2][c], T[r4 + 3][c] };
    *(u16x4*)(KVT + ((size_t)b * DD + td * 64 + c) * LKV + tk * 64 + r4) = w;
  }
}

// ---------------------------------------------------------------------------
// Kernel 3 (new): O[b] = A[b] @ KV[b], B from pre-transposed bf16 KVT.
// BM=128, BN=256, BK=64, 8 waves. A reg-staged (fp32->bf16, padded LDS),
// B via global_load_lds w/ both-sides chunk XOR swizzle.
// ---------------------------------------------------------------------------
__global__ __launch_bounds__(512) void gemm_av2_kernel(const float* __restrict__ A,
                                                       const unsigned short* __restrict__ KVT,
                                                       float* __restrict__ O)
{
  __shared__ unsigned short Asm[128][72];       // padded: conflict-free frag reads
  __shared__ unsigned short Bsm[256 * 64];      // linear (global_load_lds dest), swizzled
  const int b  = blockIdx.z;
  const int mi = blockIdx.y;     // 0..7  (LQ tiles of 128)
  const int nj = blockIdx.x;     // 0..1  (D tiles of 256)
  const int tid  = threadIdx.x;
  const int lane = tid & 63;
  const int wid  = tid >> 6;               // 0..7
  const int wr = (wid >> 2) * 64;          // wave row (2 rows of waves)
  const int wc = (wid & 3) * 64;           // wave col (4 cols of waves)

  const float* Ab = A + (size_t)b * LQ * LKV + (size_t)mi * 128 * LKV;
  const unsigned short* Bb = KVT + ((size_t)b * DD + nj * 256) * LKV;

  f32x4 acc[4][4] = {};

  for (int ks = 0; ks < LKV; ks += 64) {
    __syncthreads();
    // ---- stage A: 128 x 64 fp32 -> bf16 (4 f4 loads/thread) ----
#pragma unroll
    for (int i = 0; i < 4; ++i) {
      int idx = tid + i * 512;          // 0..2047
      int r   = idx >> 4;               // 0..127
      int k4  = (idx & 15) << 2;        // 0,4,..,60
      f4 v = *(const f4*)(Ab + (size_t)r * LKV + ks + k4);
      u16x4 h;
#pragma unroll
      for (int u = 0; u < 4; ++u) h[u] = f2bf(v[u]);
      *(u16x4*)&Asm[r][k4] = h;
    }
    // ---- stage B: 256 rows(d) x 64 kv bf16 via global_load_lds ----
    // chunk cc (1KB) = rows cc*8..cc*8+7; lane l -> row cc*8 + (l>>3),
    // 16B slot (l&7); physical slot holds global slot s^(row&7).
#pragma unroll
    for (int c = 0; c < 4; ++c) {
      int cc = wid * 4 + c;                    // 0..31
      int dd = cc * 8 + (lane >> 3);           // 0..255
      int ss = (lane & 7) ^ (dd & 7);
      const unsigned short* g = Bb + (size_t)dd * LKV + ks + ss * 8;
      gload16(g, &Bsm[cc * 512]);              // wave-uniform LDS base (1KB chunk)
    }
    __syncthreads();

    // ---- compute: 2 k-subtiles of 32 ----
#pragma unroll
    for (int kk = 0; kk < 64; kk += 32) {
      const int kf = kk + ((lane >> 4) << 3);  // k offset 0..56
      const int cl = kf >> 3;                  // logical 16B slot 0..7
      bf16x8 af[4], bfv[4];
#pragma unroll
      for (int m = 0; m < 4; ++m)
        af[m] = *(const bf16x8*)&Asm[wr + m * 16 + (lane & 15)][kf];
#pragma unroll
      for (int n = 0; n < 4; ++n) {
        int dd = wc + n * 16 + (lane & 15);
        int sp = cl ^ (dd & 7);
        bfv[n] = *(const bf16x8*)&Bsm[dd * 64 + sp * 8];
      }
#pragma unroll
      for (int m = 0; m < 4; ++m)
#pragma unroll
        for (int n = 0; n < 4; ++n)
          acc[m][n] = __builtin_amdgcn_mfma_f32_16x16x32_bf16(af[m], bfv[n], acc[m][n], 0, 0, 0);
    }
  }

  float* Ob = O + (size_t)b * LQ * DD;
#pragma unroll
  for (int m = 0; m < 4; ++m) {
    int row0 = mi * 128 + wr + m * 16 + ((lane >> 4) << 2);
#pragma unroll
    for (int n = 0; n < 4; ++n) {
      int col = nj * 256 + wc + n * 16 + (lane & 15);
#pragma unroll
      for (int j = 0; j < 4; ++j)
        Ob[(size_t)(row0 + j) * DD + col] = acc[m][n][j];
    }
  }
}

// ---------------------------------------------------------------------------
// Fallback kernel 3 (round-1 version) in case ws is too small for KVT.
// ---------------------------------------------------------------------------
__global__ __launch_bounds__(256) void gemm_av_kernel(const float* __restrict__ A,
                                                      const float* __restrict__ KV,
                                                      float* __restrict__ O)
{
  __shared__ unsigned short Ab[128][PAD], Bt[128][PAD];
  const int b  = blockIdx.z;
  const int mi = blockIdx.y;
  const int nj = blockIdx.x;
  const int tid  = threadIdx.x;
  const int lane = tid & 63;
  const int wid  = tid >> 6;
  const int wr = (wid >> 1) * 64;
  const int wc = (wid & 1) * 64;

  const float* Arow = A  + (size_t)b * LQ * LKV + (size_t)mi * 128 * LKV;
  const float* Kb   = KV + (size_t)b * LKV * DD;

  f32x4 acc[4][4] = {};

  for (int ks = 0; ks < LKV; ks += 32) {
    __syncthreads();
#pragma unroll
    for (int i = 0; i < 4; ++i) {
      int idx = tid + i * 256;
      {
        int r  = idx >> 3;
        int k4 = (idx & 7) << 2;
        f4 av = *(const f4*)(Arow + (size_t)r * LKV + ks + k4);
        u16x4 h;
#pragma unroll
        for (int u = 0; u < 4; ++u) h[u] = f2bf(av[u]);
        *(u16x4*)&Ab[r][k4] = h;
      }
      {
        int kr = idx >> 5;
        int c4 = (idx & 31) << 2;
        f4 kv = *(const f4*)(Kb + (size_t)(ks + kr) * DD + nj * 128 + c4);
        unsigned short hv[4];
#pragma unroll
        for (int u = 0; u < 4; ++u) hv[u] = f2bf(kv[u]);
#pragma unroll
        for (int u = 0; u < 4; ++u) {
          int uu = (u + kr) & 3;
          Bt[c4 + uu][kr] = hv[uu];
        }
      }
    }
    __syncthreads();

    const int kf = (lane >> 4) << 3;
    bf16x8 af[4], bfv[4];
#pragma unroll
    for (int m = 0; m < 4; ++m)
      af[m] = *(const bf16x8*)&Ab[wr + m * 16 + (lane & 15)][kf];
#pragma unroll
    for (int n = 0; n < 4; ++n)
      bfv[n] = *(const bf16x8*)&Bt[wc + n * 16 + (lane & 15)][kf];
#pragma unroll
    for (int m = 0; m < 4; ++m)
#pragma unroll
      for (int n = 0; n < 4; ++n)
        acc[m][n] = __builtin_amdgcn_mfma_f32_16x16x32_bf16(af[m], bfv[n], acc[m][n], 0, 0, 0);
  }

  float* Ob = O + (size_t)b * LQ * DD;
#pragma unroll
  for (int m = 0; m < 4; ++m) {
    int row0 = mi * 128 + wr + m * 16 + ((lane >> 4) << 2);
#pragma unroll
    for (int n = 0; n < 4; ++n) {
      int col = nj * 128 + wc + n * 16 + (lane & 15);
#pragma unroll
      for (int j = 0; j < 4; ++j)
        Ob[(size_t)(row0 + j) * DD + col] = acc[m][n][j];
    }
  }
}

// ---------------------------------------------------------------------------
extern "C" void kernel_launch(void* const* d_in, const int* in_sizes, int n_in,
                              void* d_out, int out_size, void* d_ws, size_t ws_size,
                              hipStream_t stream) {
  const float* Q  = (const float*)d_in[0];
  const float* KV = (const float*)d_in[1];
  float* out  = (float*)d_out;                       // B*LQ*D
  float* attn = out + (size_t)NB * LQ * DD;          // B*LQ*LKV

  const size_t kvt_bytes = (size_t)NB * DD * LKV * sizeof(unsigned short); // 33.5 MB
  const bool use_ws = (ws_size >= kvt_bytes);

  // 1) raw scores -> attn region
  gemm_qk_kernel<<<dim3((LQ / 128) * (LKV / 128), NB), 256, 0, stream>>>(Q, KV, attn);
  if (use_ws) {
    unsigned short* KVT = (unsigned short*)d_ws;
    kvt_prep_kernel<<<dim3(DD / 64, LKV / 64, NB), 256, 0, stream>>>(KV, KVT);
    // 2) softmax in place
    softmax_kernel<<<dim3(NB * LQ), 256, 0, stream>>>(attn);
    // 3) output = attn @ KV (bf16 B from KVT)
    gemm_av2_kernel<<<dim3(DD / 256, LQ / 128, NB), 512, 0, stream>>>(attn, KVT, out);
  } else {
    softmax_kernel<<<dim3(NB * LQ), 256, 0, stream>>>(attn);
    gemm_av_kernel<<<dim3(DD / 128, LQ / 128, NB), 256, 0, stream>>>(attn, KV, out);
  }
}